// Round 9
// baseline (1854.660 us; speedup 1.0000x reference)
//
#include <hip/hip_runtime.h>
#include <hip/hip_fp16.h>

// ---------------------------------------------------------------------------
// 2-layer tanh RNN, B=256, T=512, H=512, D=64, + FC(512->1).
//   proj0 -> rec0 -> proj1 -> rec1 (see R7). rec = 1 chain/CU, 512 thr, 8 waves.
//
// ROUND 9 = ROUND 8 with the shufflevector-constant-index compile fix only
// (p-loops expanded via DOT8 macro; __builtin_shufflevector demands literal
// indices at parse time, #pragma unroll is too late).
// Hybrid MFMA + VALU-dot recurrence engine:
//   g0,g1 : MFMA, 32 AGPR frags (asm "a"), all 16 j. Prework j=0,1 pre-barrier.
//   g2    : MFMA, j<12 from LDS slots 0..11; j>=12 from L2 pool (4 frags,
//           plain loads consumed as "v" -- NOT the R5 "+a" path).
//   g3    : j<12 (ring k 0..383) via VALU fdot2: lane owns row 64w+48+(l>>2),
//           ring-halfs [96(l&3), +96) from replicated hbuf; 12 uint4 weights.
//           Merge: shfl_xor 1,2 + one shfl. j=12..15 MFMA from LDS 12..15.
// MFMA/CU/step: 512 -> 416 (2017 cy); LDS B-traffic 128 KB/step; VALU ~480 cy.
// Acc stays "+v" (R5/R6 lesson: "+a" + v_accvgpr_read = missing hazard waits).
// ---------------------------------------------------------------------------

typedef _Float16 h2 __attribute__((ext_vector_type(2)));
typedef _Float16 h8 __attribute__((ext_vector_type(8)));
typedef float    f4 __attribute__((ext_vector_type(4)));

#define HID   512
#define TSEQ  512
#define NB    256
#define NWAVE 8
#define NRSL  32   // AGPR reg slots per wave
#define NLSL  16   // LDS slots per wave (0..11 g2, 12..15 g3)
#define NGSL  4    // L2/global slots per wave (g2 j=12..15)
#define NWV   12   // uint4 of VALU weights per lane

#define MFMA_A(accv, av, bv) \
  asm("v_mfma_f32_16x16x32_f16 %0, %1, %2, %0" : "+v"(accv) : "v"(av), "a"(bv))
#define MFMA_V(accv, av, bv) \
  asm("v_mfma_f32_16x16x32_f16 %0, %1, %2, %0" : "+v"(accv) : "v"(av), "v"(bv))

#if defined(__has_builtin)
#if __has_builtin(__builtin_amdgcn_fdot2)
#define FDOT2(a, b, c) __builtin_amdgcn_fdot2((a), (b), (c), false)
#endif
#endif
#ifndef FDOT2
static __device__ __forceinline__ float FDOT2(h2 a, h2 b, float c) {
  return c + (float)a[0] * (float)b[0] + (float)a[1] * (float)b[1];
}
#endif

#define HP(v, i) __builtin_shufflevector((v), (v), 2 * (i), 2 * (i) + 1)
// 8-half dot: literal lane-pair indices (shufflevector needs parse-time consts)
#define DOT8(wx, hx, accv)                      \
  do {                                          \
    accv = FDOT2(HP(wx, 0), HP(hx, 0), accv);   \
    accv = FDOT2(HP(wx, 1), HP(hx, 1), accv);   \
    accv = FDOT2(HP(wx, 2), HP(hx, 2), accv);   \
    accv = FDOT2(HP(wx, 3), HP(hx, 3), accv);   \
  } while (0)

// ---------------- workspace layout (bytes) ----------------
static const size_t OFF_P   = 0;                       // [131072][512] fp16  134217728
static const size_t OFF_B0  = 134217728;               // W_ih0 fp16 [512][64]    65536
static const size_t OFF_B1  = OFF_B0 + 65536;          // W_ih1 fp16 [512][512]  524288
static const size_t OFF_R0  = OFF_B1 + 524288;         // 8*32*64*16 = 262144
static const size_t OFF_L0  = OFF_R0 + 262144;         // 8*16*64*16 = 131072
static const size_t OFF_G0  = OFF_L0 + 131072;         // 8*4*64*16  =  32768
static const size_t OFF_V0  = OFF_G0 + 32768;          // 8*64*12*16 =  98304
static const size_t OFF_R1  = OFF_V0 + 98304;
static const size_t OFF_L1  = OFF_R1 + 262144;
static const size_t OFF_G1  = OFF_L1 + 131072;
static const size_t OFF_V1  = OFF_G1 + 32768;
static const size_t OFF_BS0 = OFF_V1 + 98304;          // bias0 f32 [512]
static const size_t OFF_BS1 = OFF_BS0 + 2048;          // bias1 f32 [512]

// ---------------- prep kernels ----------------
__global__ void bias_kernel(const float* __restrict__ bih0, const float* __restrict__ bhh0,
                            const float* __restrict__ bih1, const float* __restrict__ bhh1,
                            float* __restrict__ bias0, float* __restrict__ bias1) {
  int i = threadIdx.x;  // block 512
  bias0[i] = bih0[i] + bhh0[i];
  bias1[i] = bih1[i] + bhh1[i];
}

__global__ void cvt_half_kernel(const float* __restrict__ in, _Float16* __restrict__ outp, int n) {
  int i = blockIdx.x * 256 + threadIdx.x;
  if (i < n) outp[i] = (_Float16)in[i];
}

__device__ __forceinline__ h8 cvt8(const float* src) {
  h8 v;
#pragma unroll
  for (int i = 0; i < 8; ++i) v[i] = (_Float16)src[i];
  return v;
}

// Pack W_hh (fp32 [512][512]) into the rec kernel's pools.
// MFMA fragment (wave w, tile g, kstep kk), lane l:
//   8 halfs = W[64w + 16g + (l&15)][32kk + ((l>>4)&3)*8 .. +8);  j = (kk-2w) mod 16.
// VALU weights: lane l of wave w, uint4 q (0..11): row = 64w+48+(l>>2),
//   ring half window [8q,8q+8) of the lane's [96(l&3),+96): jv = 3(l&3)+(q>>2),
//   kk = (2w+jv)&15, k0 = 32kk + (q&3)*8.
__global__ void pack_rec_kernel(const float* __restrict__ W, uint4* __restrict__ BregP,
                                uint4* __restrict__ BldsP, uint4* __restrict__ GGlob,
                                uint4* __restrict__ WVP) {
  int id = blockIdx.x * 256 + threadIdx.x;   // 32768 threads
  if (id < 16384) {                          // BregP: g0,g1 all j
    int l = id & 63, s = (id >> 6) & 31, w = id >> 11;
    int j = s >> 1, g = s & 1;
    int kk = (2 * w + j) & 15;
    int n = 64 * w + 16 * g + (l & 15);
    int k0 = 32 * kk + ((l >> 4) & 3) * 8;
    BregP[(w * NRSL + s) * 64 + l] = __builtin_bit_cast(uint4, cvt8(W + (size_t)n * HID + k0));
  } else if (id < 24576) {                   // BldsP: s<12 -> g2 j=s; s>=12 -> g3 j=s
    int idx = id - 16384;
    int l = idx & 63, s = (idx >> 6) & 15, w = idx >> 10;
    int j = s, g = (s < 12) ? 2 : 3;
    int kk = (2 * w + j) & 15;
    int n = 64 * w + 16 * g + (l & 15);
    int k0 = 32 * kk + ((l >> 4) & 3) * 8;
    BldsP[(w * NLSL + s) * 64 + l] = __builtin_bit_cast(uint4, cvt8(W + (size_t)n * HID + k0));
  } else if (id < 26624) {                   // GGlob: g2, j = 12+s
    int idx = id - 24576;
    int l = idx & 63, s = (idx >> 6) & 3, w = idx >> 8;
    int j = 12 + s;
    int kk = (2 * w + j) & 15;
    int n = 64 * w + 32 + (l & 15);
    int k0 = 32 * kk + ((l >> 4) & 3) * 8;
    GGlob[(w * NGSL + s) * 64 + l] = __builtin_bit_cast(uint4, cvt8(W + (size_t)n * HID + k0));
  } else if (id < 32768) {                   // WVP: VALU weights
    int idx = id - 26624;                    // 6144
    int w = idx / 768;
    int r2 = idx - 768 * w;
    int l = r2 / 12;
    int q = r2 - 12 * l;
    int row = 64 * w + 48 + (l >> 2);
    int jv = 3 * (l & 3) + (q >> 2);
    int kk = (2 * w + jv) & 15;
    int k0 = 32 * kk + (q & 3) * 8;
    WVP[((size_t)(w * 64 + l)) * NWV + q] = __builtin_bit_cast(uint4, cvt8(W + (size_t)row * HID + k0));
  }
}

// ---------------- projection GEMM (MFMA f16) ----------------
template <typename AT, int K>
__global__ __launch_bounds__(256, 2) void proj_kernel(const AT* A, const _Float16* __restrict__ Bw,
                                                      _Float16* C, const float* __restrict__ bias) {
  __shared__ _Float16 At[64][40];
  __shared__ _Float16 Bt[512][40];
  const int tid = threadIdx.x;
  const int m0 = blockIdx.x * 64;
  const int wv = tid >> 6;
  const int l = tid & 63;
  const int n0 = wv * 128;
  const int lm = l & 15;
  const int lq = l >> 4;

  f4 acc[4][8];
#pragma unroll
  for (int i = 0; i < 4; ++i)
#pragma unroll
    for (int j = 0; j < 8; ++j) acc[i][j] = (f4){0.f, 0.f, 0.f, 0.f};

  const int arow = tid >> 2;
  const int kq = (tid & 3) * 8;

  for (int k0 = 0; k0 < K; k0 += 32) {
    if (sizeof(AT) == 4) {
      const float* ap = (const float*)A + (size_t)(m0 + arow) * K + k0 + kq;
      *(h8*)&At[arow][kq] = cvt8(ap);
    } else {
      *(h8*)&At[arow][kq] = *(const h8*)((const _Float16*)A + (size_t)(m0 + arow) * K + k0 + kq);
    }
#pragma unroll
    for (int rr = 0; rr < 8; ++rr) {
      int rrow = arow + rr * 64;
      *(h8*)&Bt[rrow][kq] = *(const h8*)(Bw + (size_t)rrow * K + k0 + kq);
    }
    __syncthreads();
    h8 af[4];
#pragma unroll
    for (int mm = 0; mm < 4; ++mm) af[mm] = *(const h8*)&At[mm * 16 + lm][lq * 8];
#pragma unroll
    for (int nn = 0; nn < 8; ++nn) {
      h8 bf = *(const h8*)&Bt[n0 + nn * 16 + lm][lq * 8];
#pragma unroll
      for (int mm = 0; mm < 4; ++mm)
        acc[mm][nn] = __builtin_amdgcn_mfma_f32_16x16x32_f16(af[mm], bf, acc[mm][nn], 0, 0, 0);
    }
    __syncthreads();
  }
#pragma unroll
  for (int nn = 0; nn < 8; ++nn) {
    int col = n0 + nn * 16 + lm;
    float bv = bias[col];
#pragma unroll
    for (int mm = 0; mm < 4; ++mm) {
#pragma unroll
      for (int r = 0; r < 4; ++r) {
        int row = m0 + mm * 16 + lq * 4 + r;
        C[(size_t)row * HID + col] = (_Float16)(acc[mm][nn][r] + bv);
      }
    }
  }
}

// ---------------- recurrence kernel (hybrid MFMA + VALU dot) ----------------
template <bool WRITE_H, bool DO_FC>
__global__ __launch_bounds__(512, 2) void rec_kernel(
    const _Float16* __restrict__ P, _Float16* __restrict__ Pout,
    const uint4* __restrict__ BregP, const uint4* __restrict__ BldsP,
    const uint4* GGlob, const uint4* __restrict__ WVP,
    const float* __restrict__ Wfc, const float* __restrict__ bfc, float* __restrict__ out) {
  __shared__ __align__(16) uint4 Blds[NWAVE * NLSL * 64];   // 131072 B
  __shared__ __align__(16) _Float16 hbuf2[2][2 * HID];      // 4 KB, dbuf, 2x replicated
  __shared__ __align__(16) float hxch[NWAVE][64];           // 2 KB, per-wave private
  __shared__ float red[NWAVE];
  const int tid = threadIdx.x;
  const int b = blockIdx.x;
  const int w = tid >> 6, l = tid & 63, lq = l >> 4;

  // one-time loads: breg_a only as asm "a" -> AGPR (128); VALU weights -> VGPR (48).
  h8 breg_a[NRSL];
#pragma unroll
  for (int i = 0; i < NRSL; ++i)
    breg_a[i] = __builtin_bit_cast(h8, BregP[(w * NRSL + i) * 64 + l]);
  uint4 wv[NWV];
#pragma unroll
  for (int i = 0; i < NWV; ++i)
    wv[i] = WVP[((size_t)(w * 64 + l)) * NWV + i];
  const uint4* bl = &Blds[w * NLSL * 64 + l];        // slot s at bl[s*64]
#pragma unroll
  for (int s = 0; s < NLSL; ++s)
    Blds[(w * NLSL + s) * 64 + l] = BldsP[(w * NLSL + s) * 64 + l];
  const uint4* gp = GGlob + (size_t)(w * NGSL) * 64 + l;   // slot s at gp[s*64]

  hbuf2[0][tid] = (_Float16)0.f;          // h0 = 0, both replicas
  hbuf2[0][tid + 512] = (_Float16)0.f;
  __syncthreads();

  const _Float16* prow = P + (size_t)b * TSEQ * HID;
  _Float16* pw = WRITE_H ? (Pout + (size_t)b * TSEQ * HID + tid) : nullptr;
  unsigned short xp_cur = *(const unsigned short*)(prow + tid);
  const int abase = 64 * w + 8 * lq;        // halfs; A-frag j at hb + abase + 32*j
  const int vbase = 64 * w + 96 * (l & 3);  // VALU h window base (ring halfs)
  float lv = 0.f;

  f4 acc0, acc1, acc2, acc3;

  // ---- prologue: prework for t=0 (h0 = 0) ----
  acc0 = (f4){0.f, 0.f, 0.f, 0.f}; acc1 = acc0; acc2 = acc0; acc3 = acc0;
  {
    const _Float16* hbn = hbuf2[0];
    h8 A0 = *(const h8*)(hbn + abase);
    h8 A1 = *(const h8*)(hbn + abase + 32);
    h8 bf0 = __builtin_bit_cast(h8, bl[0 * 64]);
    h8 bf1 = __builtin_bit_cast(h8, bl[1 * 64]);
    MFMA_A(acc0, A0, breg_a[0]); MFMA_A(acc1, A0, breg_a[1]); MFMA_V(acc2, A0, bf0);
    MFMA_A(acc0, A1, breg_a[2]); MFMA_A(acc1, A1, breg_a[3]); MFMA_V(acc2, A1, bf1);
  }

#pragma unroll 1
  for (int t = 0; t < TSEQ; ++t) {
    __syncthreads();   // all waves' h(t) published (j=0,1 of g0,g1,g2 done)
    int tn = (t + 1 < TSEQ) ? t + 1 : t;
    unsigned short xp_next = *(const unsigned short*)(prow + (size_t)tn * HID + tid);
    const _Float16* hb = hbuf2[t & 1];

    // L2-pool loads for g2 j=12..15 (consumed as "v" much later)
    uint4 gq0 = gp[0 * 64], gq1 = gp[1 * 64], gq2 = gp[2 * 64], gq3 = gp[3 * 64];

#define AFRAG(J) (*(const h8*)(hb + abase + 32 * (J)))
#define LDSF(S) __builtin_bit_cast(h8, bl[(S) * 64])
    // j = 2..11: g0,g1 AGPR; g2 LDS slot j
    { h8 A = AFRAG(2);  MFMA_A(acc0, A, breg_a[4]);  MFMA_A(acc1, A, breg_a[5]);
      h8 bf = LDSF(2);  MFMA_V(acc2, A, bf); }
    { h8 A = AFRAG(3);  MFMA_A(acc0, A, breg_a[6]);  MFMA_A(acc1, A, breg_a[7]);
      h8 bf = LDSF(3);  MFMA_V(acc2, A, bf); }
    { h8 A = AFRAG(4);  MFMA_A(acc0, A, breg_a[8]);  MFMA_A(acc1, A, breg_a[9]);
      h8 bf = LDSF(4);  MFMA_V(acc2, A, bf); }
    { h8 A = AFRAG(5);  MFMA_A(acc0, A, breg_a[10]); MFMA_A(acc1, A, breg_a[11]);
      h8 bf = LDSF(5);  MFMA_V(acc2, A, bf); }

    // VALU g3 dots: ring k window [96(l&3), +96), 4 chunks x 12 fdot2
    float vacc = 0.f;
#pragma unroll
    for (int c = 0; c < 4; ++c) {
      uint4 hc0 = *(const uint4*)(hb + vbase + 24 * c);
      uint4 hc1 = *(const uint4*)(hb + vbase + 24 * c + 8);
      uint4 hc2 = *(const uint4*)(hb + vbase + 24 * c + 16);
      h8 h0 = __builtin_bit_cast(h8, hc0), h1 = __builtin_bit_cast(h8, hc1),
         h2v = __builtin_bit_cast(h8, hc2);
      h8 w0 = __builtin_bit_cast(h8, wv[3 * c]), w1 = __builtin_bit_cast(h8, wv[3 * c + 1]),
         w2 = __builtin_bit_cast(h8, wv[3 * c + 2]);
      DOT8(w0, h0, vacc);
      DOT8(w1, h1, vacc);
      DOT8(w2, h2v, vacc);
    }

    { h8 A = AFRAG(6);  MFMA_A(acc0, A, breg_a[12]); MFMA_A(acc1, A, breg_a[13]);
      h8 bf = LDSF(6);  MFMA_V(acc2, A, bf); }
    { h8 A = AFRAG(7);  MFMA_A(acc0, A, breg_a[14]); MFMA_A(acc1, A, breg_a[15]);
      h8 bf = LDSF(7);  MFMA_V(acc2, A, bf); }
    { h8 A = AFRAG(8);  MFMA_A(acc0, A, breg_a[16]); MFMA_A(acc1, A, breg_a[17]);
      h8 bf = LDSF(8);  MFMA_V(acc2, A, bf); }
    { h8 A = AFRAG(9);  MFMA_A(acc0, A, breg_a[18]); MFMA_A(acc1, A, breg_a[19]);
      h8 bf = LDSF(9);  MFMA_V(acc2, A, bf); }
    { h8 A = AFRAG(10); MFMA_A(acc0, A, breg_a[20]); MFMA_A(acc1, A, breg_a[21]);
      h8 bf = LDSF(10); MFMA_V(acc2, A, bf); }
    { h8 A = AFRAG(11); MFMA_A(acc0, A, breg_a[22]); MFMA_A(acc1, A, breg_a[23]);
      h8 bf = LDSF(11); MFMA_V(acc2, A, bf); }
    // j = 12..15: g0,g1 AGPR; g2 from L2 (gq); g3 MFMA from LDS slot j
    { h8 A = AFRAG(12); MFMA_A(acc0, A, breg_a[24]); MFMA_A(acc1, A, breg_a[25]);
      h8 b2 = __builtin_bit_cast(h8, gq0); MFMA_V(acc2, A, b2);
      h8 b3 = LDSF(12); MFMA_V(acc3, A, b3); }
    { h8 A = AFRAG(13); MFMA_A(acc0, A, breg_a[26]); MFMA_A(acc1, A, breg_a[27]);
      h8 b2 = __builtin_bit_cast(h8, gq1); MFMA_V(acc2, A, b2);
      h8 b3 = LDSF(13); MFMA_V(acc3, A, b3); }
    { h8 A = AFRAG(14); MFMA_A(acc0, A, breg_a[28]); MFMA_A(acc1, A, breg_a[29]);
      h8 b2 = __builtin_bit_cast(h8, gq2); MFMA_V(acc2, A, b2);
      h8 b3 = LDSF(14); MFMA_V(acc3, A, b3); }
    { h8 A = AFRAG(15); MFMA_A(acc0, A, breg_a[30]); MFMA_A(acc1, A, breg_a[31]);
      h8 b2 = __builtin_bit_cast(h8, gq3); MFMA_V(acc2, A, b2);
      h8 b3 = LDSF(15); MFMA_V(acc3, A, b3); }
#undef AFRAG
#undef LDSF

    // VALU merge: lanes within a row-group differ in l&3 -> butterfly xor 1,2
    vacc += __shfl_xor(vacc, 1, 64);
    vacc += __shfl_xor(vacc, 2, 64);
    // tail thread l>=48 needs row (l&15)'s sum, held by lane 4*(l&15)
    float tailv = __shfl(vacc, (l & 15) << 2, 64);

    // extraction: lanes<16 hold n=64w+16g+l in acc{g}[0] (acc3 = g3 partial)
    if (l < 16) {
      hxch[w][l]      = acc0[0];
      hxch[w][16 + l] = acc1[0];
      hxch[w][32 + l] = acc2[0];
      hxch[w][48 + l] = acc3[0];
    }
    asm volatile("s_waitcnt lgkmcnt(0)" ::: "memory");
    float hr = hxch[w][l];   // n = 64w + l = tid
    if (l >= 48) hr += tailv;

    float v = tanhf(hr + (float)__builtin_bit_cast(_Float16, xp_cur));
    lv = v;
    _Float16 hw = (_Float16)v;
    _Float16* hbn = hbuf2[(t + 1) & 1];
    hbn[tid] = hw;
    hbn[tid + 512] = hw;
    if (WRITE_H) pw[(size_t)t * HID] = hw;
    asm volatile("s_waitcnt lgkmcnt(0)" ::: "memory");   // own slice visible to own reads

    // ---- prework for step t+1 (pre-barrier: own-slice j=0,1) ----
    acc0 = (f4){0.f, 0.f, 0.f, 0.f}; acc1 = acc0; acc2 = acc0; acc3 = acc0;
    {
      h8 A0 = *(const h8*)(hbn + abase);
      h8 A1 = *(const h8*)(hbn + abase + 32);
      h8 bf0 = __builtin_bit_cast(h8, bl[0 * 64]);
      h8 bf1 = __builtin_bit_cast(h8, bl[1 * 64]);
      MFMA_A(acc0, A0, breg_a[0]); MFMA_A(acc1, A0, breg_a[1]); MFMA_V(acc2, A0, bf0);
      MFMA_A(acc0, A1, breg_a[2]); MFMA_A(acc1, A1, breg_a[3]); MFMA_V(acc2, A1, bf1);
    }
    xp_cur = xp_next;
  }

  if (DO_FC) {
    float fc = lv * Wfc[tid];
#pragma unroll
    for (int off = 32; off; off >>= 1) fc += __shfl_down(fc, off, 64);
    if (l == 0) red[w] = fc;
    __syncthreads();
    if (tid == 0) {
      float s = bfc[0];
#pragma unroll
      for (int i = 0; i < NWAVE; ++i) s += red[i];
      out[b] = s;
    }
  }
}

// ---------------- launcher ----------------
extern "C" void kernel_launch(void* const* d_in, const int* in_sizes, int n_in,
                              void* d_out, int out_size, void* d_ws, size_t ws_size,
                              hipStream_t stream) {
  const float* x    = (const float*)d_in[0];
  const float* Wih0 = (const float*)d_in[1];
  const float* Whh0 = (const float*)d_in[2];
  const float* bih0 = (const float*)d_in[3];
  const float* bhh0 = (const float*)d_in[4];
  const float* Wih1 = (const float*)d_in[5];
  const float* Whh1 = (const float*)d_in[6];
  const float* bih1 = (const float*)d_in[7];
  const float* bhh1 = (const float*)d_in[8];
  const float* Wfc  = (const float*)d_in[9];
  const float* bfc  = (const float*)d_in[10];
  float* out = (float*)d_out;
  char* ws = (char*)d_ws;

  _Float16* P  = (_Float16*)(ws + OFF_P);
  _Float16* B0 = (_Float16*)(ws + OFF_B0);
  _Float16* B1 = (_Float16*)(ws + OFF_B1);
  uint4* R0 = (uint4*)(ws + OFF_R0);
  uint4* L0 = (uint4*)(ws + OFF_L0);
  uint4* G0 = (uint4*)(ws + OFF_G0);
  uint4* V0 = (uint4*)(ws + OFF_V0);
  uint4* R1 = (uint4*)(ws + OFF_R1);
  uint4* L1 = (uint4*)(ws + OFF_L1);
  uint4* G1 = (uint4*)(ws + OFF_G1);
  uint4* V1 = (uint4*)(ws + OFF_V1);
  float* bias0 = (float*)(ws + OFF_BS0);
  float* bias1 = (float*)(ws + OFF_BS1);

  bias_kernel<<<1, 512, 0, stream>>>(bih0, bhh0, bih1, bhh1, bias0, bias1);
  cvt_half_kernel<<<128, 256, 0, stream>>>(Wih0, B0, 512 * 64);
  cvt_half_kernel<<<1024, 256, 0, stream>>>(Wih1, B1, 512 * 512);
  pack_rec_kernel<<<128, 256, 0, stream>>>(Whh0, R0, L0, G0, V0);
  pack_rec_kernel<<<128, 256, 0, stream>>>(Whh1, R1, L1, G1, V1);

  proj_kernel<float, 64><<<2048, 256, 0, stream>>>(x, B0, P, bias0);
  rec_kernel<true, false><<<NB, 512, 0, stream>>>(P, P, R0, L0, G0, V0, nullptr, nullptr, nullptr);
  proj_kernel<_Float16, 512><<<2048, 256, 0, stream>>>(P, B1, P, bias1);
  rec_kernel<false, true><<<NB, 512, 0, stream>>>(P, nullptr, R1, L1, G1, V1, Wfc, bfc, out);
}